// Round 1
// baseline (893.897 us; speedup 1.0000x reference)
//
#include <hip/hip_runtime.h>
#include <math.h>
#include <float.h>

// Problem constants (EMAVectorQuantizer eval path)
//   z: [8, 64, 64, 64] fp32  (B, C=EMBED_DIM, H, W)
//   weight: [4096, 64] fp32
//   N rows = 8*64*64 = 32768, codes = 4096, dim = 64
//
// d_out layout (flat fp32, return order):
//   [0 .. 2097152)                z_q  [B,C,H,W]
//   [2097152]                     loss
//   [2097153]                     perplexity
//   [2097154 .. +134217728)       encodings [32768, 4096]
//   [136314882 .. +32768)         encoding_indices (stored as float)

#define ZQ_OFF   0
#define LOSS_OFF 2097152
#define PERP_OFF 2097153
#define ENC_OFF  2097154
#define IDX_OFF  136314882ULL
#define BETA     0.25f

// ws layout: [0..4) float loss accumulator; [16..16+16384) int hist[4096]

__global__ __launch_bounds__(512, 4) void vq_main(
    const float* __restrict__ z, const float* __restrict__ w,
    float* __restrict__ out, float* __restrict__ loss_ws, int* __restrict__ hist)
{
    __shared__ float s_wnorm[4096];
    __shared__ float s_best[8][64];
    __shared__ int   s_bidx[8][64];
    __shared__ int   s_fidx[64];

    const int tid  = threadIdx.x;
    const int lane = tid & 63;
    const int wave = tid >> 6;
    const int base = blockIdx.x * 64;        // rows [base, base+64), row n = b*4096 + h*64 + w
    const int bb   = base >> 12;             // b
    const int hh   = (base & 4095) >> 6;     // h   (w = lane)

    // ---- ||w||^2 into LDS (each thread: 8 codes, contiguous 2KB) ----
    {
        const float4* w4 = (const float4*)w;
        #pragma unroll
        for (int j = 0; j < 8; ++j) {
            int c = tid * 8 + j;
            float s = 0.f;
            #pragma unroll
            for (int k = 0; k < 16; ++k) {
                float4 v = w4[c * 16 + k];
                s += v.x * v.x + v.y * v.y + v.z * v.z + v.w * v.w;
            }
            s_wnorm[c] = s;
        }
    }

    // ---- z row into registers: zr[c] = z[bb, c, hh, lane] ----
    float zr[64];
    {
        const float* zb = z + ((size_t)bb * 64 * 64 + hh) * 64 + lane;
        #pragma unroll
        for (int c = 0; c < 64; ++c) zr[c] = zb[(size_t)c * 4096];
    }
    __syncthreads();

    float* enc = out + ENC_OFF;   // byte offset % 8 == 0 -> float2-aligned

    // ---- scan this wave's 512-code slice; interleave encodings zero-fill ----
    float best = FLT_MAX;
    int   bidx = 0;
    for (int i = 0; i < 512; ++i) {
        int c0 = wave * 512 + i;
        int cu = __builtin_amdgcn_readfirstlane(c0);   // wave-uniform -> s_load path
        const float* wr = w + (size_t)cu * 64;
        float a0 = 0.f, a1 = 0.f, a2 = 0.f, a3 = 0.f;
        #pragma unroll
        for (int d = 0; d < 64; d += 4) {
            a0 = fmaf(zr[d],     wr[d],     a0);
            a1 = fmaf(zr[d + 1], wr[d + 1], a1);
            a2 = fmaf(zr[d + 2], wr[d + 2], a2);
            a3 = fmaf(zr[d + 3], wr[d + 3], a3);
        }
        float score = fmaf(-2.f, (a0 + a1) + (a2 + a3), s_wnorm[cu]);
        if (score < best) { best = score; bidx = cu; }  // strict < keeps lowest index on ties

        // zero-fill: 256 float2 per thread over 512 iterations covers 64 rows x 4096 cols
        if (i & 1) {
            int slot = (i >> 1) * 512 + tid;     // 0..131071
            int r    = slot >> 11;               // row in block (2048 float2 per row)
            int c2   = slot & 2047;
            float2* p = (float2*)(enc + ((size_t)(base + r) << 12)) + c2;
            *p = make_float2(0.f, 0.f);
        }
    }

    s_best[wave][lane] = best;
    s_bidx[wave][lane] = bidx;
    __threadfence_block();
    __syncthreads();   // also drains the zero-fill stores (vmcnt(0) before s_barrier)

    if (wave == 0) {
        float fb = s_best[0][lane];
        int   fi = s_bidx[0][lane];
        #pragma unroll
        for (int g = 1; g < 8; ++g) {
            float b2 = s_best[g][lane];
            int   i2 = s_bidx[g][lane];
            if (b2 < fb) { fb = b2; fi = i2; }   // strict <: lower wave = lower codes wins ties
        }
        s_fidx[lane] = fi;
    }
    __syncthreads();

    const int fidx = s_fidx[lane];

    if (wave == 0) {
        // indices (as float)
        out[IDX_OFF + (size_t)(base + lane)] = (float)fidx;
        // z_q (STE rounding: z + (q - z)) + commitment-loss partial
        const float* qrow = w + (size_t)fidx * 64;
        float* zqb = out + ZQ_OFF + ((size_t)bb * 64 * 64 + hh) * 64 + lane;
        float lsum = 0.f;
        #pragma unroll
        for (int c = 0; c < 64; ++c) {
            float q = qrow[c];
            float diff = q - zr[c];
            lsum += diff * diff;
            zqb[(size_t)c * 4096] = zr[c] + (q - zr[c]);
        }
        #pragma unroll
        for (int off = 32; off > 0; off >>= 1)
            lsum += __shfl_down(lsum, off, 64);
        if (lane == 0) atomicAdd(loss_ws, lsum);
    } else if (wave == 1) {
        atomicAdd(&hist[fidx], 1);
        // set the one-hot 1.0 (zero-fill already drained at the barrier above)
        enc[((size_t)(base + lane) << 12) + fidx] = 1.0f;
    }
}

__global__ void vq_finalize(const int* __restrict__ hist,
                            const float* __restrict__ loss_ws,
                            float* __restrict__ out)
{
    __shared__ float red[256];
    const int tid = threadIdx.x;
    float s = 0.f;
    #pragma unroll
    for (int j = 0; j < 16; ++j) {
        int c = tid + j * 256;
        float p = (float)hist[c] * (1.0f / 32768.0f);
        s += p * logf(p + 1e-10f);
    }
    red[tid] = s;
    __syncthreads();
    for (int off = 128; off > 0; off >>= 1) {
        if (tid < off) red[tid] += red[tid + off];
        __syncthreads();
    }
    if (tid == 0) {
        out[LOSS_OFF] = BETA * loss_ws[0] / 2097152.0f;
        out[PERP_OFF] = expf(-red[0]);
    }
}

extern "C" void kernel_launch(void* const* d_in, const int* in_sizes, int n_in,
                              void* d_out, int out_size, void* d_ws, size_t ws_size,
                              hipStream_t stream)
{
    const float* z = (const float*)d_in[0];
    const float* w = (const float*)d_in[1];
    float* out     = (float*)d_out;
    float* loss_ws = (float*)d_ws;
    int*   hist    = (int*)((char*)d_ws + 16);

    hipMemsetAsync(d_ws, 0, 16 + 4096 * sizeof(int), stream);
    vq_main<<<512, 512, 0, stream>>>(z, w, out, loss_ws, hist);
    vq_finalize<<<1, 256, 0, stream>>>(hist, loss_ws, out);
}

// Round 2
// 742.833 us; speedup vs baseline: 1.2034x; 1.2034x over previous
//
#include <hip/hip_runtime.h>
#include <math.h>
#include <float.h>

// EMAVectorQuantizer eval path.
//   z: [8, 64, 64, 64] fp32  (B, C=d=64, H, W);  weight: [4096, 64] fp32
//   N = 32768 rows, K = 4096 codes.
//
// d_out (flat fp32): z_q[2097152] | loss | perplexity | encodings[32768*4096] | indices[32768]
#define ZQ_OFF   0
#define LOSS_OFF 2097152
#define PERP_OFF 2097153
#define ENC_OFF  2097154
#define IDX_OFF  136314882ULL
#define BETA     0.25f

// ws layout: [0..4) loss fp32 acc | [4..8) ticket int | [16..16+16384) hist int[4096]
//            [16400 .. +16384) wnorm fp32[4096]          (needs ws_size >= 32784 B)

__global__ void vq_wnorm(const float* __restrict__ w, float* __restrict__ wnorm) {
    int c = blockIdx.x * 256 + threadIdx.x;
    const float4* w4 = (const float4*)(w + ((size_t)c << 6));
    float s = 0.f;
    #pragma unroll
    for (int k = 0; k < 16; ++k) { float4 v = w4[k]; s += v.x*v.x + v.y*v.y + v.z*v.z + v.w*v.w; }
    wnorm[c] = s;
}

__global__ __launch_bounds__(256, 2) void vq_main(
    const float* __restrict__ z, const float* __restrict__ w,
    const float* __restrict__ wnorm, float* __restrict__ out,
    float* __restrict__ loss_ws, int* __restrict__ ticket, int* __restrict__ hist)
{
    __shared__ float zT[64][64];        // [d][row-in-block], 16 KB
    __shared__ float wl[128 * 65];      // [c_local][d], pad 65 -> conflict-free b32 reads, 33.3 KB
    __shared__ int   s_widx[64];
    __shared__ int   s_flag;

    const int tx   = threadIdx.x;
    const int tcol = tx & 31;           // code column: codes tcol + {0,32,64,96} within a chunk
    const int trow = tx >> 5;           // row group: rows trow*8 .. trow*8+7
    const int base = blockIdx.x * 64;   // global rows [base, base+64)
    const int bb   = base >> 12;        // b
    const int hh   = (base & 4095) >> 6;// h  (w coordinate = row-in-block)

    // ---- stage z slice transposed: zT[d][wcol] = z[bb][d][hh][wcol] ----
    #pragma unroll
    for (int j = 0; j < 4; ++j) {
        int f4 = j * 256 + tx;                 // 0..1023 float4 slots
        int d  = f4 >> 4, k = f4 & 15;
        float4 v = *(const float4*)(z + (((size_t)bb * 64 + d) * 64 + hh) * 64 + k * 4);
        *(float4*)&zT[d][k * 4] = v;
    }

    float best[8]; int bidx[8];
    #pragma unroll
    for (int i = 0; i < 8; ++i) { best[i] = FLT_MAX; bidx[i] = 0; }

    float* enc = out + ENC_OFF;   // 8-byte aligned region -> float2 stores

    for (int ch = 0; ch < 32; ++ch) {
        const int cbase = ch << 7;
        __syncthreads();   // wl safe to overwrite

        // stage weight chunk [cbase, cbase+128) into padded LDS
        #pragma unroll
        for (int j = 0; j < 8; ++j) {
            int f4 = j * 256 + tx;             // 0..2047
            int c  = f4 >> 4, k = f4 & 15;
            float4 v = *(const float4*)(w + ((size_t)(cbase + c) << 6) + k * 4);
            float* p = &wl[c * 65 + k * 4];
            p[0] = v.x; p[1] = v.y; p[2] = v.z; p[3] = v.w;
        }
        // prefetch ||w||^2 for this thread's 4 codes (L2-hot)
        float wn0 = wnorm[cbase + tcol];
        float wn1 = wnorm[cbase + tcol + 32];
        float wn2 = wnorm[cbase + tcol + 64];
        float wn3 = wnorm[cbase + tcol + 96];
        // interleaved zero-fill of encodings (1 MB/block over 32 chunks)
        #pragma unroll
        for (int j = 0; j < 16; ++j) {
            int f2 = (ch << 12) + j * 256 + tx;    // 0..131071 float2 slots
            int r  = f2 >> 11, c2 = f2 & 2047;
            *((float2*)(enc + ((size_t)(base + r) << 12)) + c2) = make_float2(0.f, 0.f);
        }
        __syncthreads();

        float acc[8][4];
        #pragma unroll
        for (int i = 0; i < 8; ++i)
            { acc[i][0] = 0.f; acc[i][1] = 0.f; acc[i][2] = 0.f; acc[i][3] = 0.f; }

        #pragma unroll 4
        for (int d = 0; d < 64; ++d) {
            float4 za = *(const float4*)&zT[d][trow * 8];
            float4 zb = *(const float4*)&zT[d][trow * 8 + 4];
            float zr0[8] = { za.x, za.y, za.z, za.w, zb.x, zb.y, zb.z, zb.w };
            float wv[4];
            wv[0] = wl[(tcol      ) * 65 + d];
            wv[1] = wl[(tcol + 32 ) * 65 + d];
            wv[2] = wl[(tcol + 64 ) * 65 + d];
            wv[3] = wl[(tcol + 96 ) * 65 + d];
            #pragma unroll
            for (int i = 0; i < 8; ++i)
                #pragma unroll
                for (int j = 0; j < 4; ++j)
                    acc[i][j] = fmaf(zr0[i], wv[j], acc[i][j]);
        }

        // fold into running argmin (index-ascending: j then chunk order)
        #pragma unroll
        for (int i = 0; i < 8; ++i) {
            float s0 = fmaf(-2.f, acc[i][0], wn0);
            if (s0 < best[i]) { best[i] = s0; bidx[i] = cbase + tcol; }
            float s1 = fmaf(-2.f, acc[i][1], wn1);
            if (s1 < best[i]) { best[i] = s1; bidx[i] = cbase + tcol + 32; }
            float s2 = fmaf(-2.f, acc[i][2], wn2);
            if (s2 < best[i]) { best[i] = s2; bidx[i] = cbase + tcol + 64; }
            float s3 = fmaf(-2.f, acc[i][3], wn3);
            if (s3 < best[i]) { best[i] = s3; bidx[i] = cbase + tcol + 96; }
        }
    }

    // ---- cross-thread argmin reduce (reuse wl as [64][32] float2) ----
    __syncthreads();                       // also drains all zero-fill stores
    float2* red = (float2*)wl;
    #pragma unroll
    for (int i = 0; i < 8; ++i)
        red[(trow * 8 + i) * 32 + tcol] = make_float2(best[i], __int_as_float(bidx[i]));
    __syncthreads();

    if (tx < 64) {
        float b = FLT_MAX; int bi = 0x7fffffff;
        for (int c = 0; c < 32; ++c) {
            float2 v = red[tx * 32 + c];
            int vi = __float_as_int(v.y);
            if (v.x < b || (v.x == b && vi < bi)) { b = v.x; bi = vi; }
        }
        s_widx[tx] = bi;
        out[IDX_OFF + (size_t)(base + tx)] = (float)bi;
        atomicAdd(&hist[bi], 1);
        enc[((size_t)(base + tx) << 12) + bi] = 1.0f;   // zero-fill drained at barrier above
    }
    __syncthreads();

    // ---- z_q (STE rounding) + commitment loss partial ----
    {
        const int row = tx & 63;
        const int dg  = tx >> 6;           // 4 waves x 16 d each
        const int wi  = s_widx[row];
        const float* qrow = w + ((size_t)wi << 6);
        float lsum = 0.f;
        #pragma unroll
        for (int dd = 0; dd < 16; ++dd) {
            int d = dg * 16 + dd;
            float q  = qrow[d];
            float zv = zT[d][row];
            float diff = q - zv;
            lsum += diff * diff;
            out[ZQ_OFF + (((size_t)bb * 64 + d) * 64 + hh) * 64 + row] = zv + (q - zv);
        }
        #pragma unroll
        for (int off = 32; off > 0; off >>= 1) lsum += __shfl_down(lsum, off, 64);
        if ((tx & 63) == 0) atomicAdd(loss_ws, lsum);
    }

    // ---- fused finalize: last block computes loss scalar + perplexity ----
    __syncthreads();
    if (tx == 0) {
        __threadfence();
        int old = atomicAdd(ticket, 1);
        s_flag = (old == 511) ? 1 : 0;
    }
    __syncthreads();
    if (s_flag) {
        __threadfence();
        float s = 0.f;
        #pragma unroll
        for (int j = 0; j < 16; ++j) {
            int c = tx + j * 256;
            int cnt = atomicAdd(&hist[c], 0);          // device-coherent read
            float p = (float)cnt * (1.f / 32768.f);
            s += p * logf(p + 1e-10f);
        }
        float* fr = wl;
        fr[tx] = s;
        __syncthreads();
        for (int off = 128; off > 0; off >>= 1) {
            if (tx < off) fr[tx] += fr[tx + off];
            __syncthreads();
        }
        if (tx == 0) {
            out[LOSS_OFF] = BETA * atomicAdd(loss_ws, 0.f) / 2097152.f;
            out[PERP_OFF] = expf(-fr[0]);
        }
    }
}

extern "C" void kernel_launch(void* const* d_in, const int* in_sizes, int n_in,
                              void* d_out, int out_size, void* d_ws, size_t ws_size,
                              hipStream_t stream)
{
    const float* z = (const float*)d_in[0];
    const float* w = (const float*)d_in[1];
    float* out     = (float*)d_out;
    float* loss_ws = (float*)d_ws;
    int*   ticket  = (int*)((char*)d_ws + 4);
    int*   hist    = (int*)((char*)d_ws + 16);
    float* wnorm   = (float*)((char*)d_ws + 16400);

    hipMemsetAsync(d_ws, 0, 16 + 4096 * sizeof(int), stream);
    vq_wnorm<<<16, 256, 0, stream>>>(w, wnorm);
    vq_main<<<512, 256, 0, stream>>>(z, w, wnorm, out, loss_ws, ticket, hist);
}

// Round 3
// 742.233 us; speedup vs baseline: 1.2043x; 1.0008x over previous
//
#include <hip/hip_runtime.h>
#include <math.h>
#include <float.h>

// EMAVectorQuantizer eval path.
//   z: [8, 64, 64, 64] fp32  (B, C=d=64, H, W);  weight: [4096, 64] fp32
//   N = 32768 rows, K = 4096 codes.
//
// d_out (flat fp32): z_q[2097152] | loss | perplexity | encodings[32768*4096] | indices[32768]
#define ZQ_OFF   0
#define LOSS_OFF 2097152
#define PERP_OFF 2097153
#define ENC_OFF  2097154
#define IDX_OFF  136314882ULL
#define BETA     0.25f

// ws layout: [0..4) loss fp32 acc | [4..8) ticket int | [16..16+16384) hist int[4096]
//            [16400 .. +16384) wnorm fp32[4096]

__global__ void vq_wnorm(const float* __restrict__ w, float* __restrict__ wnorm) {
    int c = blockIdx.x * 256 + threadIdx.x;
    const float4* w4 = (const float4*)(w + ((size_t)c << 6));
    float s = 0.f;
    #pragma unroll
    for (int k = 0; k < 16; ++k) { float4 v = w4[k]; s += v.x*v.x + v.y*v.y + v.z*v.z + v.w*v.w; }
    wnorm[c] = s;
}

// Block: 256 threads = 8 row-groups (trow) x 32 col-groups (tcol).
// Per-thread tile: 8 rows x 8 codes. Chunk = 256 codes, d staged in 2 x 32 slices.
__global__ __launch_bounds__(256, 2) void vq_main(
    const float* __restrict__ z, const float* __restrict__ w,
    const float* __restrict__ wnorm, float* __restrict__ out,
    float* __restrict__ loss_ws, int* __restrict__ ticket, int* __restrict__ hist)
{
    __shared__ float zD[64][64];     // [d][w-row], b128 reads are 2-addr broadcast
    __shared__ float wl[256 * 36];   // [c_local][36]: 32-d slice + pad (stride 36 spreads banks)
    __shared__ int   s_widx[64];
    __shared__ int   s_flag;

    const int tx   = threadIdx.x;
    const int tcol = tx & 31;            // codes tcol + 32k, k=0..7, within chunk
    const int trow = tx >> 5;            // rows trow*8 .. trow*8+7 within block
    const int base = blockIdx.x * 64;    // global rows [base, base+64)
    const int bb   = base >> 12;         // b
    const int hh   = (base & 4095) >> 6; // h   (w coordinate = row-in-block)

    // ---- stage zD[d][wcol] = z[bb][d][hh][wcol], b128 in and out ----
    #pragma unroll
    for (int j = 0; j < 4; ++j) {
        int f4 = j * 256 + tx;           // 0..1023
        int d  = f4 >> 4, w4i = f4 & 15;
        float4 v = *(const float4*)(z + (((size_t)bb * 64 + d) * 64 + hh) * 64 + w4i * 4);
        *(float4*)&zD[d][w4i * 4] = v;
    }

    float best[8]; int bidx[8];
    #pragma unroll
    for (int i = 0; i < 8; ++i) { best[i] = FLT_MAX; bidx[i] = 0; }

    float* enc = out + ENC_OFF;          // 8-byte aligned region -> float2 stores

    for (int ch = 0; ch < 16; ++ch) {
        const int cbase = ch << 8;
        float wn[8];
        #pragma unroll
        for (int k = 0; k < 8; ++k) wn[k] = wnorm[cbase + tcol + 32 * k];

        float acc[8][8];
        #pragma unroll
        for (int i = 0; i < 8; ++i)
            #pragma unroll
            for (int k = 0; k < 8; ++k) acc[i][k] = 0.f;

        #pragma unroll
        for (int s = 0; s < 2; ++s) {
            __syncthreads();             // wl safe to overwrite
            // stage w[cbase..cbase+256)[s*32 .. s*32+32) -> wl
            #pragma unroll
            for (int j = 0; j < 8; ++j) {
                int f4 = j * 256 + tx;   // 0..2047
                int c  = f4 >> 3, q = f4 & 7;
                float4 v = ((const float4*)w)[(size_t)(cbase + c) * 16 + s * 8 + q];
                *(float4*)&wl[c * 36 + q * 4] = v;
            }
            // interleaved zero-fill of encodings (1 MB/block over 32 rounds)
            #pragma unroll
            for (int j = 0; j < 16; ++j) {
                int f2 = ((ch * 2 + s) * 16 + j) * 256 + tx;   // 0..131071
                int r  = f2 >> 11, c2 = f2 & 2047;
                *((float2*)(enc + ((size_t)(base + r) << 12)) + c2) = make_float2(0.f, 0.f);
            }
            __syncthreads();

            // compute 32 d's: 8 groups of 4
            #pragma unroll
            for (int dg = 0; dg < 8; ++dg) {
                const int d0 = s * 32 + dg * 4;
                float4 zv0[4], zv1[4];
                #pragma unroll
                for (int e = 0; e < 4; ++e) {
                    zv0[e] = *(const float4*)&zD[d0 + e][trow * 8];
                    zv1[e] = *(const float4*)&zD[d0 + e][trow * 8 + 4];
                }
                float4 wv[8];
                #pragma unroll
                for (int k = 0; k < 8; ++k)
                    wv[k] = *(const float4*)&wl[(tcol + 32 * k) * 36 + dg * 4];
                #pragma unroll
                for (int k = 0; k < 8; ++k) {
                    #pragma unroll
                    for (int e = 0; e < 4; ++e) {
                        const float wf = (e == 0) ? wv[k].x : (e == 1) ? wv[k].y
                                        : (e == 2) ? wv[k].z : wv[k].w;
                        acc[0][k] = fmaf(zv0[e].x, wf, acc[0][k]);
                        acc[1][k] = fmaf(zv0[e].y, wf, acc[1][k]);
                        acc[2][k] = fmaf(zv0[e].z, wf, acc[2][k]);
                        acc[3][k] = fmaf(zv0[e].w, wf, acc[3][k]);
                        acc[4][k] = fmaf(zv1[e].x, wf, acc[4][k]);
                        acc[5][k] = fmaf(zv1[e].y, wf, acc[5][k]);
                        acc[6][k] = fmaf(zv1[e].z, wf, acc[6][k]);
                        acc[7][k] = fmaf(zv1[e].w, wf, acc[7][k]);
                    }
                }
            }
        }

        // fold into running argmin (codes ascending per thread: k then chunk order)
        #pragma unroll
        for (int i = 0; i < 8; ++i) {
            #pragma unroll
            for (int k = 0; k < 8; ++k) {
                float sc = fmaf(-2.f, acc[i][k], wn[k]);
                if (sc < best[i]) { best[i] = sc; bidx[i] = cbase + tcol + 32 * k; }
            }
        }
    }

    // ---- cross-thread argmin reduce (reuse wl as [64][32] float2) ----
    __syncthreads();                       // also drains all zero-fill stores
    float2* red = (float2*)wl;
    #pragma unroll
    for (int i = 0; i < 8; ++i)
        red[(trow * 8 + i) * 32 + tcol] = make_float2(best[i], __int_as_float(bidx[i]));
    __syncthreads();

    if (tx < 64) {
        float b = FLT_MAX; int bi = 0x7fffffff;
        for (int c = 0; c < 32; ++c) {
            float2 v = red[tx * 32 + c];
            int vi = __float_as_int(v.y);
            if (v.x < b || (v.x == b && vi < bi)) { b = v.x; bi = vi; }
        }
        s_widx[tx] = bi;
        out[IDX_OFF + (size_t)(base + tx)] = (float)bi;
        atomicAdd(&hist[bi], 1);
        enc[((size_t)(base + tx) << 12) + bi] = 1.0f;   // zero-fill drained at barrier above
    }
    __syncthreads();

    // ---- z_q (STE rounding) + commitment loss partial ----
    {
        const int row = tx & 63;
        const int dg  = tx >> 6;           // 4 waves x 16 d each
        const int wi  = s_widx[row];
        const float* qrow = w + ((size_t)wi << 6);
        float lsum = 0.f;
        #pragma unroll
        for (int dd = 0; dd < 16; ++dd) {
            int d = dg * 16 + dd;
            float q  = qrow[d];
            float zv = zD[d][row];
            float diff = q - zv;
            lsum += diff * diff;
            out[ZQ_OFF + (((size_t)bb * 64 + d) * 64 + hh) * 64 + row] = zv + (q - zv);
        }
        #pragma unroll
        for (int off = 32; off > 0; off >>= 1) lsum += __shfl_down(lsum, off, 64);
        if ((tx & 63) == 0) atomicAdd(loss_ws, lsum);
    }

    // ---- fused finalize: last block computes loss scalar + perplexity ----
    __syncthreads();
    if (tx == 0) {
        __threadfence();
        int old = atomicAdd(ticket, 1);
        s_flag = (old == 511) ? 1 : 0;
    }
    __syncthreads();
    if (s_flag) {
        __threadfence();
        float s = 0.f;
        #pragma unroll
        for (int j = 0; j < 16; ++j) {
            int c = tx + j * 256;
            int cnt = atomicAdd(&hist[c], 0);          // device-coherent read
            float p = (float)cnt * (1.f / 32768.f);
            s += p * logf(p + 1e-10f);
        }
        float* fr = wl;
        fr[tx] = s;
        __syncthreads();
        for (int off = 128; off > 0; off >>= 1) {
            if (tx < off) fr[tx] += fr[tx + off];
            __syncthreads();
        }
        if (tx == 0) {
            out[LOSS_OFF] = BETA * atomicAdd(loss_ws, 0.f) / 2097152.f;
            out[PERP_OFF] = expf(-fr[0]);
        }
    }
}

extern "C" void kernel_launch(void* const* d_in, const int* in_sizes, int n_in,
                              void* d_out, int out_size, void* d_ws, size_t ws_size,
                              hipStream_t stream)
{
    const float* z = (const float*)d_in[0];
    const float* w = (const float*)d_in[1];
    float* out     = (float*)d_out;
    float* loss_ws = (float*)d_ws;
    int*   ticket  = (int*)((char*)d_ws + 4);
    int*   hist    = (int*)((char*)d_ws + 16);
    float* wnorm   = (float*)((char*)d_ws + 16400);

    hipMemsetAsync(d_ws, 0, 16 + 4096 * sizeof(int), stream);
    vq_wnorm<<<16, 256, 0, stream>>>(w, wnorm);
    vq_main<<<512, 256, 0, stream>>>(z, w, wnorm, out, loss_ws, ticket, hist);
}